// Round 1
// baseline (1037.780 us; speedup 1.0000x reference)
//
#include <hip/hip_runtime.h>

// MultiHeadAttention: B=2, S=2048, D=1024, H=16, Dh=64.
// Outputs: out fp32 [2,2048,1024] then attn fp32 [2,16,2048,2048] (concat flat).
//
// Pipeline:
//  1) cvt: fp32->bf16 (query/key split hi+lo for precision; value, weights plain)
//  2) gemm_bt<true,0>:  Q = Xq @ Wq^T + bq  -> hi/lo bf16 [B,H,S,Dh]
//     gemm_bt<true,0>:  K likewise
//     gemm_bt<false,1>: V = Xv @ Wv^T + bv  -> bf16 [B,H,Dh,S]   (transposed for PV)
//  3) attn_fused: two-pass online softmax per 128-row q-block; writes attn fp32
//     and AO = attn@V in bf16 [B,S,D]
//  4) gemm_bt<false,2>: out = AO @ Wo^T + bo (fp32)

typedef unsigned short u16;
typedef __attribute__((ext_vector_type(8))) short bh8;     // 8 x bf16 (4 VGPRs)
typedef __attribute__((ext_vector_type(4))) float f32x4;   // MFMA C/D
typedef __attribute__((ext_vector_type(4))) u16 u16x4;
typedef __attribute__((ext_vector_type(4))) float f4;

#define S_LEN 2048
#define DH 64
#define NH 16
#define DM 1024
#define MROWS 4096  // B*S

__device__ __forceinline__ u16 f2b(float f) {  // RNE fp32->bf16
  unsigned u = __float_as_uint(f);
  unsigned r = (u + 0x7fffu + ((u >> 16) & 1u)) >> 16;
  return (u16)r;
}
__device__ __forceinline__ float b2f(u16 h) {
  return __uint_as_float(((unsigned)h) << 16);
}
__device__ __forceinline__ f32x4 mfma16(bh8 a, bh8 b, f32x4 c) {
  return __builtin_amdgcn_mfma_f32_16x16x32_bf16(a, b, c, 0, 0, 0);
}
__device__ __forceinline__ void gld_lds16(const u16* g, u16* l) {
  __builtin_amdgcn_global_load_lds((__attribute__((address_space(1))) void*)g,
                                   (__attribute__((address_space(3))) void*)l, 16, 0, 0);
}

// ---------------- convert kernels ----------------
__global__ __launch_bounds__(256) void cvt_plain(const float* __restrict__ s,
                                                 u16* __restrict__ d, int n4) {
  int i = blockIdx.x * 256 + threadIdx.x;
  if (i >= n4) return;
  f4 v = ((const f4*)s)[i];
  u16x4 o;
#pragma unroll
  for (int j = 0; j < 4; ++j) o[j] = f2b(v[j]);
  ((u16x4*)d)[i] = o;
}

__global__ __launch_bounds__(256) void cvt_split(const float* __restrict__ s,
                                                 u16* __restrict__ dh,
                                                 u16* __restrict__ dl, int n4) {
  int i = blockIdx.x * 256 + threadIdx.x;
  if (i >= n4) return;
  f4 v = ((const f4*)s)[i];
  u16x4 oh, ol;
#pragma unroll
  for (int j = 0; j < 4; ++j) {
    u16 hi = f2b(v[j]);
    oh[j] = hi;
    ol[j] = f2b(v[j] - b2f(hi));
  }
  ((u16x4*)dh)[i] = oh;
  ((u16x4*)dl)[i] = ol;
}

// ---------------- generic 128x128 gemm, B given transposed ([N][K]) ----------------
// MODE 0: out hi/lo bf16 to [B,H,S,Dh] (q/k). MODE 1: bf16 to [B,H,Dh,S] (v^T).
// MODE 2: fp32 to [M][N].
template <bool SPLIT_A, int MODE>
__global__ __launch_bounds__(256) void gemm_bt(
    const u16* __restrict__ Ah, const u16* __restrict__ Al,
    const u16* __restrict__ Bt, const float* __restrict__ bias,
    void* __restrict__ out0, void* __restrict__ out1, int M, int N, int K) {
  extern __shared__ u16 smem[];
  u16* sA = smem;                                   // [128][64]
  u16* sAl = SPLIT_A ? (smem + 8192) : nullptr;     // [128][64]
  u16* sB = smem + (SPLIT_A ? 16384 : 8192);        // [128][64]

  int t = threadIdx.x;
  int w = t >> 6, l = t & 63;
  int lr = l & 15, lg = l >> 4;
  int wr = (w >> 1) * 64, wc = (w & 1) * 64;
  int row0 = blockIdx.y * 128, col0 = blockIdx.x * 128;

  f32x4 acc[4][4];
#pragma unroll
  for (int i = 0; i < 4; ++i)
#pragma unroll
    for (int j = 0; j < 4; ++j) acc[i][j] = (f32x4){0.f, 0.f, 0.f, 0.f};

  for (int k0 = 0; k0 < K; k0 += 64) {
#pragma unroll
    for (int i = 0; i < 4; ++i) {
      int li = i * 256 + t;
      int tr = li >> 3;             // tile row 0..127
      int kc = (li & 7) * 8;        // k element 0..56
      gld_lds16(Ah + (size_t)(row0 + tr) * K + k0 + kc, sA + li * 8);
      if (SPLIT_A) gld_lds16(Al + (size_t)(row0 + tr) * K + k0 + kc, sAl + li * 8);
      gld_lds16(Bt + (size_t)(col0 + tr) * K + k0 + kc, sB + li * 8);
    }
    __syncthreads();
#pragma unroll
    for (int cc = 0; cc < 2; ++cc) {
      bh8 af[4], bf[4];
#pragma unroll
      for (int i = 0; i < 4; ++i)
        af[i] = *(const bh8*)&sA[(wr + i * 16 + lr) * 64 + cc * 32 + lg * 8];
#pragma unroll
      for (int j = 0; j < 4; ++j)
        bf[j] = *(const bh8*)&sB[(wc + j * 16 + lr) * 64 + cc * 32 + lg * 8];
#pragma unroll
      for (int i = 0; i < 4; ++i)
#pragma unroll
        for (int j = 0; j < 4; ++j) acc[i][j] = mfma16(af[i], bf[j], acc[i][j]);
      if (SPLIT_A) {
        bh8 alf[4];
#pragma unroll
        for (int i = 0; i < 4; ++i)
          alf[i] = *(const bh8*)&sAl[(wr + i * 16 + lr) * 64 + cc * 32 + lg * 8];
#pragma unroll
        for (int i = 0; i < 4; ++i)
#pragma unroll
          for (int j = 0; j < 4; ++j) acc[i][j] = mfma16(alf[i], bf[j], acc[i][j]);
      }
    }
    __syncthreads();
  }

#pragma unroll
  for (int i = 0; i < 4; ++i)
#pragma unroll
    for (int j = 0; j < 4; ++j) {
      int gn = col0 + wc + j * 16 + lr;
      float bv = bias[gn];
      int gm0 = row0 + wr + i * 16 + lg * 4;
      if (MODE == 2) {
        float* o = (float*)out0;
#pragma unroll
        for (int r = 0; r < 4; ++r)
          o[(size_t)(gm0 + r) * N + gn] = acc[i][j][r] + bv;
      } else if (MODE == 0) {
#pragma unroll
        for (int r = 0; r < 4; ++r) {
          int gm = gm0 + r;
          int bb = gm >> 11, ss = gm & 2047, hh = gn >> 6, dd = gn & 63;
          size_t idx = (((size_t)bb * NH + hh) * S_LEN + ss) * DH + dd;
          float v = acc[i][j][r] + bv;
          u16 hi = f2b(v);
          ((u16*)out0)[idx] = hi;
          ((u16*)out1)[idx] = f2b(v - b2f(hi));
        }
      } else {  // MODE 1: V^T [B,H,Dh,S]; 4 consecutive s -> one 8B store
        int bb = gm0 >> 11, ss = gm0 & 2047, hh = gn >> 6, dd = gn & 63;
        size_t idx = (((size_t)bb * NH + hh) * DH + dd) * S_LEN + ss;
        u16x4 o;
#pragma unroll
        for (int r = 0; r < 4; ++r) o[r] = f2b(acc[i][j][r] + bv);
        *(u16x4*)((u16*)out0 + idx) = o;
      }
    }
}

// ---------------- fused attention ----------------
// Grid: B*H*(S/128) blocks, 256 threads (4 waves x 32 q-rows each).
// Pass 1: online row max/sum over K tiles (hi-precision scores only).
// Pass 2: exact scores (qh*kh + ql*kh + qh*kl), write attn fp32, PV via LDS transpose.
__global__ __launch_bounds__(256) void attn_fused(
    const u16* __restrict__ Qh, const u16* __restrict__ Ql,
    const u16* __restrict__ Kh, const u16* __restrict__ Kl,
    const u16* __restrict__ VT, float* __restrict__ attn, u16* __restrict__ AO) {
  int t = threadIdx.x, w = t >> 6, l = t & 63;
  int lr = l & 15, lg = l >> 4;
  int id = blockIdx.x;
  int qt = id & 15, bh = id >> 4;
  int b = bh >> 4, h = bh & 15;
  size_t hoff = (size_t)bh * S_LEN * DH;
  int qrow0 = qt * 128 + w * 32;
  const float scale = 0.125f;

  // Q fragments in registers (hi+lo), 2 row-frags x 2 k-chunks
  bh8 aqh[2][2], aql[2][2];
#pragma unroll
  for (int ri = 0; ri < 2; ++ri) {
    const u16* qp = Qh + hoff + (size_t)(qrow0 + ri * 16 + lr) * DH;
    const u16* qlp = Ql + hoff + (size_t)(qrow0 + ri * 16 + lr) * DH;
#pragma unroll
    for (int cc = 0; cc < 2; ++cc) {
      aqh[ri][cc] = *(const bh8*)(qp + cc * 32 + lg * 8);
      aql[ri][cc] = *(const bh8*)(qlp + cc * 32 + lg * 8);
    }
  }

  float mrow[2][4], lrow[2][4];
#pragma unroll
  for (int ri = 0; ri < 2; ++ri)
#pragma unroll
    for (int r = 0; r < 4; ++r) { mrow[ri][r] = -1e30f; lrow[ri][r] = 0.f; }

  // ---- pass 1: stats (hi-only scores; fine for m/l) ----
  for (int kt = 0; kt < 32; ++kt) {
    const u16* kb = Kh + hoff + (size_t)kt * 64 * DH;
    f32x4 sf[2][4];
#pragma unroll
    for (int c4 = 0; c4 < 4; ++c4) {
      const u16* kp = kb + (size_t)(c4 * 16 + lr) * DH;
      bh8 bk0 = *(const bh8*)(kp + lg * 8);
      bh8 bk1 = *(const bh8*)(kp + 32 + lg * 8);
#pragma unroll
      for (int ri = 0; ri < 2; ++ri) {
        f32x4 a = (f32x4){0.f, 0.f, 0.f, 0.f};
        a = mfma16(aqh[ri][0], bk0, a);
        a = mfma16(aqh[ri][1], bk1, a);
        sf[ri][c4] = a;
      }
    }
#pragma unroll
    for (int ri = 0; ri < 2; ++ri)
#pragma unroll
      for (int r = 0; r < 4; ++r) {
        float s0 = sf[ri][0][r] * scale, s1 = sf[ri][1][r] * scale;
        float s2 = sf[ri][2][r] * scale, s3 = sf[ri][3][r] * scale;
        float tm = fmaxf(fmaxf(s0, s1), fmaxf(s2, s3));
#pragma unroll
        for (int d = 1; d < 16; d <<= 1) tm = fmaxf(tm, __shfl_xor(tm, d));
        float nm = fmaxf(mrow[ri][r], tm);
        float ps = __expf(s0 - nm) + __expf(s1 - nm) + __expf(s2 - nm) + __expf(s3 - nm);
#pragma unroll
        for (int d = 1; d < 16; d <<= 1) ps += __shfl_xor(ps, d);
        lrow[ri][r] = lrow[ri][r] * __expf(mrow[ri][r] - nm) + ps;
        mrow[ri][r] = nm;
      }
  }

  float invl[2][4];
#pragma unroll
  for (int ri = 0; ri < 2; ++ri)
#pragma unroll
    for (int r = 0; r < 4; ++r) invl[ri][r] = 1.0f / lrow[ri][r];

  f32x4 oacc[2][4];
#pragma unroll
  for (int ri = 0; ri < 2; ++ri)
#pragma unroll
    for (int j = 0; j < 4; ++j) oacc[ri][j] = (f32x4){0.f, 0.f, 0.f, 0.f};

  __shared__ __align__(16) u16 pbuf[4][32][72];  // per-wave P tile, padded stride

  // ---- pass 2: exact scores, write attn, PV ----
  for (int kt = 0; kt < 32; ++kt) {
    const u16* khb = Kh + hoff + (size_t)kt * 64 * DH;
    const u16* klb = Kl + hoff + (size_t)kt * 64 * DH;
#pragma unroll
    for (int c4 = 0; c4 < 4; ++c4) {
      const u16* kp = khb + (size_t)(c4 * 16 + lr) * DH;
      const u16* kp2 = klb + (size_t)(c4 * 16 + lr) * DH;
      bh8 bkh0 = *(const bh8*)(kp + lg * 8);
      bh8 bkh1 = *(const bh8*)(kp + 32 + lg * 8);
      bh8 bkl0 = *(const bh8*)(kp2 + lg * 8);
      bh8 bkl1 = *(const bh8*)(kp2 + 32 + lg * 8);
#pragma unroll
      for (int ri = 0; ri < 2; ++ri) {
        f32x4 a = (f32x4){0.f, 0.f, 0.f, 0.f};
        a = mfma16(aqh[ri][0], bkh0, a);
        a = mfma16(aql[ri][0], bkh0, a);
        a = mfma16(aqh[ri][1], bkh1, a);
        a = mfma16(aql[ri][1], bkh1, a);
        a = mfma16(aqh[ri][0], bkl0, a);
        a = mfma16(aqh[ri][1], bkl1, a);
#pragma unroll
        for (int r = 0; r < 4; ++r) {
          float p = __expf(a[r] * scale - mrow[ri][r]) * invl[ri][r];
          int prow = ri * 16 + lg * 4 + r;
          int pcol = c4 * 16 + lr;
          attn[(size_t)bh * S_LEN * S_LEN +
               (size_t)(qt * 128 + w * 32 + prow) * S_LEN + kt * 64 + pcol] = p;
          pbuf[w][prow][pcol] = f2b(p);
        }
      }
    }
    // PV: read P back in A-fragment layout (per-wave buffer; in-wave lgkmcnt ordering)
    bh8 pa[2][2];
#pragma unroll
    for (int ri = 0; ri < 2; ++ri)
#pragma unroll
      for (int cc = 0; cc < 2; ++cc)
        pa[ri][cc] = *(const bh8*)&pbuf[w][ri * 16 + lr][cc * 32 + lg * 8];
    const u16* vb = VT + (size_t)bh * DH * S_LEN + kt * 64;
#pragma unroll
    for (int j = 0; j < 4; ++j) {
      const u16* vp = vb + (size_t)(j * 16 + lr) * S_LEN;
      bh8 bv0 = *(const bh8*)(vp + lg * 8);
      bh8 bv1 = *(const bh8*)(vp + 32 + lg * 8);
#pragma unroll
      for (int ri = 0; ri < 2; ++ri) {
        oacc[ri][j] = mfma16(pa[ri][0], bv0, oacc[ri][j]);
        oacc[ri][j] = mfma16(pa[ri][1], bv1, oacc[ri][j]);
      }
    }
  }

  // AO bf16 [B,S,DM]
#pragma unroll
  for (int ri = 0; ri < 2; ++ri)
#pragma unroll
    for (int j = 0; j < 4; ++j)
#pragma unroll
      for (int r = 0; r < 4; ++r) {
        int srow = qt * 128 + w * 32 + ri * 16 + lg * 4 + r;
        int chan = h * 64 + j * 16 + lr;
        AO[((size_t)b * S_LEN + srow) * DM + chan] = f2b(oacc[ri][j][r]);
      }
}

// ---------------- launch ----------------
extern "C" void kernel_launch(void* const* d_in, const int* in_sizes, int n_in,
                              void* d_out, int out_size, void* d_ws, size_t ws_size,
                              hipStream_t stream) {
  const float* query = (const float*)d_in[0];
  const float* key = (const float*)d_in[1];
  const float* value = (const float*)d_in[2];
  const float* Wq = (const float*)d_in[3];
  const float* bq = (const float*)d_in[4];
  const float* Wk = (const float*)d_in[5];
  const float* bk = (const float*)d_in[6];
  const float* Wv = (const float*)d_in[7];
  const float* bv = (const float*)d_in[8];
  const float* Wo = (const float*)d_in[9];
  const float* bo = (const float*)d_in[10];

  float* out = (float*)d_out;
  float* attn = out + (size_t)MROWS * DM;

  char* p = (char*)d_ws;
  auto alloc = [&](size_t n) { char* r = p; p += (n + 255) & ~(size_t)255; return r; };
  const size_t XB = (size_t)MROWS * DM * 2;  // 8 MB
  const size_t WB = (size_t)DM * DM * 2;     // 2 MB
  u16* Xqh = (u16*)alloc(XB); u16* Xql = (u16*)alloc(XB);
  u16* Xkh = (u16*)alloc(XB); u16* Xkl = (u16*)alloc(XB);
  u16* Xv = (u16*)alloc(XB);
  u16* Wqb = (u16*)alloc(WB); u16* Wkb = (u16*)alloc(WB);
  u16* Wvb = (u16*)alloc(WB); u16* Wob = (u16*)alloc(WB);
  u16* Qh = (u16*)alloc(XB); u16* Ql_ = (u16*)alloc(XB);
  u16* Kh = (u16*)alloc(XB); u16* Kl_ = (u16*)alloc(XB);
  u16* VT = (u16*)alloc(XB);
  u16* AO = (u16*)alloc(XB);

  int n4x = MROWS * DM / 4, n4w = DM * DM / 4;
  cvt_split<<<n4x / 256, 256, 0, stream>>>(query, Xqh, Xql, n4x);
  cvt_split<<<n4x / 256, 256, 0, stream>>>(key, Xkh, Xkl, n4x);
  cvt_plain<<<n4x / 256, 256, 0, stream>>>(value, Xv, n4x);
  cvt_plain<<<n4w / 256, 256, 0, stream>>>(Wq, Wqb, n4w);
  cvt_plain<<<n4w / 256, 256, 0, stream>>>(Wk, Wkb, n4w);
  cvt_plain<<<n4w / 256, 256, 0, stream>>>(Wv, Wvb, n4w);
  cvt_plain<<<n4w / 256, 256, 0, stream>>>(Wo, Wob, n4w);

  dim3 gp(DM / 128, MROWS / 128);
  size_t lds3 = 3 * 128 * 64 * 2, lds2 = 2 * 128 * 64 * 2;
  gemm_bt<true, 0><<<gp, 256, lds3, stream>>>(Xqh, Xql, Wqb, bq, Qh, Ql_, MROWS, DM, DM);
  gemm_bt<true, 0><<<gp, 256, lds3, stream>>>(Xkh, Xkl, Wkb, bk, Kh, Kl_, MROWS, DM, DM);
  gemm_bt<false, 1><<<gp, 256, lds2, stream>>>(Xv, nullptr, Wvb, bv, VT, nullptr, MROWS, DM, DM);

  attn_fused<<<2 * NH * (S_LEN / 128), 256, 0, stream>>>(Qh, Ql_, Kh, Kl_, VT, attn, AO);

  gemm_bt<false, 2><<<gp, 256, lds2, stream>>>(AO, nullptr, Wob, bo, out, nullptr, MROWS, DM, DM);
}